// Round 3
// baseline (517.772 us; speedup 1.0000x reference)
//
#include <hip/hip_runtime.h>

// Problem constants: B=4, C=64, N=512*512, K=400
constexpr int BB   = 4;
constexpr int CC   = 64;
constexpr int NPIX = 512 * 512;      // 262144
constexpr int KK   = 400;

// ---------------- accum config ----------------
constexpr int PPB  = 4096;           // pixels per block
constexpr int TPX  = 128;            // pixels per LDS feature tile
constexpr int NTL  = PPB / TPX;      // 32 tiles
constexpr int TSTR = TPX + 1;        // 129 (odd): processing read banks (c+p)%32 -> free
constexpr int ATH  = 1024;           // 16 waves
constexpr int NW   = 16;             // owner classes (k & 15)
constexpr int ADUMROW = KK * CC;     // dummy sums row for deduped duplicates

// ---------------------------------------------------------------------------
// Stage 1: per-block [K x 64ch] histogram. Same compute structure as the
// previous (passing) version; memory-side changes only:
//   - per-block TILE-ORDER ROTATION: concurrent blocks read different 512B
//     pixel-offset phases -> spreads HBM channel usage (2^20-stride rows all
//     share channel bits; without skew the whole device hits ~1 channel).
//   - prefetch depth 2 (1 KB outstanding per row-stream -> longer DRAM bursts)
//   - each staging load instr covers a contiguous 256B span (A/B halves)
// grid = B * 64 chunks = 256 blocks, 1024 threads
// ---------------------------------------------------------------------------
__global__ __launch_bounds__(ATH) void accum_kernel(
    const float* __restrict__ feat,   // [B, C, N]
    const int*   __restrict__ idx,    // [B, N]
    float* __restrict__ g_sums,       // [B, K, C]
    float* __restrict__ g_cnt)        // [B, K]
{
    __shared__ float    s_sums[(KK + 1) * CC]; // 102656 B; row KK = dummy
    __shared__ float    s_cnt[KK];             //   1600 B
    __shared__ unsigned s_list[PPB];           //  16384 B: (pix<<16) | (k<<6)
    __shared__ float    s_tile[CC * TSTR];     //  33024 B
    __shared__ int      s_wcnt[NW];

    const int t     = threadIdx.x;
    const int lane  = t & 63;
    const int w     = t >> 6;                  // wave id 0..15 == owner class
    const int b     = blockIdx.x >> 6;
    const int chunk = blockIdx.x & 63;
    const int p0    = chunk * PPB;

    // zero LDS
    for (int e = t; e < (KK + 1) * CC; e += ATH) s_sums[e] = 0.0f;
    for (int e = t; e < KK; e += ATH) s_cnt[e] = 0.0f;
    __syncthreads();

    const int* idx_b = idx + b * NPIX + p0;
    const unsigned long long lmask = (1ull << lane) - 1ull;

    // ---- pass 1: per-wave ownership count; cell counts spread across waves ----
    int myCnt = 0;
    for (int j = 0; j < 64; ++j) {
        int k = idx_b[j * 64 + lane];
        if ((j >> 2) == w) atomicAdd(&s_cnt[k], 1.0f);
        myCnt += __popcll(__ballot((k & 15) == w));
    }
    if (lane == 0) s_wcnt[w] = myCnt;
    __syncthreads();

    int base = 0;
#pragma unroll
    for (int j = 0; j < NW; ++j) { int cj = s_wcnt[j]; base += (j < w) ? cj : 0; }

    // ---- pass 2: compact owned pixels (sorted by pixel), save prefix/lane ----
    int pos = base;
    int sp = 0, se = 0;   // lane j holds pos before/after pass-iteration j
    for (int j = 0; j < 64; ++j) {
        int i = j * 64 + lane;
        int k = idx_b[i];
        bool own = ((k & 15) == w);
        unsigned long long m = __ballot(own);
        if (lane == j) sp = pos;
        if (own) s_list[pos + __popcll(m & lmask)] =
                     ((unsigned)i << 16) | ((unsigned)k << 6);
        pos += __popcll(m);
        if (lane == j) se = pos;
    }

    // ---- tile loop (rotated order) ----
    const int tskew = (chunk + b * 8) & (NTL - 1);   // distinct phase per concurrent block

    const float* fb = feat + (size_t)b * CC * NPIX + p0;
    const int    cr = t >> 4;      // staging: channel row 0..63
    const int    gq = t & 15;      // staging: 4-float column group
    const float* fr = fb + (size_t)cr * NPIX;
    float* tdA = &s_tile[cr * TSTR + gq * 4];        // floats [gq*4, gq*4+4)
    float* tdB = tdA + 64;                           // floats [64+gq*4, ...)

    int ta = tskew;                          // tile for buffer cur
    int tb_ = (tskew + 1) & (NTL - 1);       // tile for buffer next
    float4 cAv = *(const float4*)(fr + ta * TPX + gq * 4);
    float4 cBv = *(const float4*)(fr + ta * TPX + 64 + gq * 4);
    float4 nAv = *(const float4*)(fr + tb_ * TPX + gq * 4);
    float4 nBv = *(const float4*)(fr + tb_ * TPX + 64 + gq * 4);

    for (int tlo = 0; tlo < NTL; ++tlo) {
        const int tl = (tlo + tskew) & (NTL - 1);
        __syncthreads();                       // prev tile fully consumed
        tdA[0] = cAv.x; tdA[1] = cAv.y; tdA[2] = cAv.z; tdA[3] = cAv.w;
        tdB[0] = cBv.x; tdB[1] = cBv.y; tdB[2] = cBv.z; tdB[3] = cBv.w;
        __syncthreads();                       // tile staged
        cAv = nAv; cBv = nBv;
        {
            int tn = (tlo + 2 + tskew) & (NTL - 1);  // wrap reads are harmless
            nAv = *(const float4*)(fr + tn * TPX + gq * 4);
            nBv = *(const float4*)(fr + tn * TPX + 64 + gq * 4);
        }

        int cur = __builtin_amdgcn_readlane(sp, 2 * tl);
        int end = __builtin_amdgcn_readlane(se, 2 * tl + 1);

        // batches of 4 pixels: reads batched ahead of writes, dedup in VALU
        for (; cur + 4 <= end; cur += 4) {
            unsigned e0 = s_list[cur + 0];
            unsigned e1 = s_list[cur + 1];
            unsigned e2 = s_list[cur + 2];
            unsigned e3 = s_list[cur + 3];

            int m0 = (int)(e0 & 0xFFFFu), m1 = (int)(e1 & 0xFFFFu);
            int m2 = (int)(e2 & 0xFFFFu), m3 = (int)(e3 & 0xFFFFu);

            float v0 = s_tile[lane * TSTR + ((e0 >> 16) & (TPX - 1))];
            float v1 = s_tile[lane * TSTR + ((e1 >> 16) & (TPX - 1))];
            float v2 = s_tile[lane * TSTR + ((e2 >> 16) & (TPX - 1))];
            float v3 = s_tile[lane * TSTR + ((e3 >> 16) & (TPX - 1))];

            bool d10 = (m1 == m0);
            bool d20 = (m2 == m0), d21 = (m2 == m1);
            bool d30 = (m3 == m0), d31 = (m3 == m1), d32 = (m3 == m2);

            v0 += d10 ? v1 : 0.0f;
            v0 += d20 ? v2 : 0.0f;
            v1 += (!d20 && d21) ? v2 : 0.0f;
            v0 += d30 ? v3 : 0.0f;
            v1 += (!d30 && d31) ? v3 : 0.0f;
            v2 += (!d30 && !d31 && d32) ? v3 : 0.0f;

            int a0 = m0 + lane;
            int a1 = d10 ? (ADUMROW + lane) : (m1 + lane);
            int a2 = (d20 || d21) ? (ADUMROW + lane) : (m2 + lane);
            int a3 = (d30 || d31 || d32) ? (ADUMROW + lane) : (m3 + lane);

            float s0 = s_sums[a0];
            float s1 = s_sums[a1];
            float s2 = s_sums[a2];
            float s3 = s_sums[a3];
            s_sums[a0] = s0 + v0;
            s_sums[a1] = s1 + v1;
            s_sums[a2] = s2 + v2;
            s_sums[a3] = s3 + v3;
        }
        // tail (<4): serial RMW (source order keeps may-alias correctness)
        for (; cur < end; ++cur) {
            unsigned e = s_list[cur];
            int a = (int)(e & 0xFFFFu) + lane;
            s_sums[a] += s_tile[lane * TSTR + ((e >> 16) & (TPX - 1))];
        }
    }
    __syncthreads();

    // ---- merge to global ----
    float* gs = g_sums + (size_t)b * KK * CC;
    for (int e = t; e < KK * CC; e += ATH) {
        float v = s_sums[e];
        if (v != 0.0f) atomicAdd(&gs[e], v);
    }
    float* gc = g_cnt + b * KK;
    for (int e = t; e < KK; e += ATH) {
        float v = s_cnt[e];
        if (v != 0.0f) atomicAdd(&gc[e], v);
    }
}

// ---------------- gather config ----------------
constexpr int GTH  = 1024;               // 16 waves
constexpr int GPIX = 4096;               // pixels per block
constexpr int MST  = 65;                 // float stride (odd -> bank (k+c)%32 spreads)

// ---------------------------------------------------------------------------
// Stage 2 (fused means + gather), channel-sweep layout:
//   wave w owns channels 4w..4w+3 and sweeps ALL 4096 pixels per channel ->
//   each (wave,channel) store stream is 16 KB CONTIGUOUS (vs 1 KB before),
//   16 streams/CU instead of 1024 -> DRAM row-activate friendly.
//   Means table [K][65] floats in LDS (divide fused at staging); per-pixel
//   reads are scattered b32 (random bank, ~2-way avg). No register transpose.
//   Per-(block,wave) start-phase rotation decorrelates the instantaneous
//   store window across the device.
// grid = B * 64 = 256 blocks, 1024 threads
// ---------------------------------------------------------------------------
__global__ __launch_bounds__(GTH) void gather_kernel(
    const float* __restrict__ g_sums, // [B, K, C]
    const float* __restrict__ g_cnt,  // [B, K]
    const int*   __restrict__ idx,    // [B, N]
    float* __restrict__ out)          // [B, C, N]
{
    __shared__ float s_mean[KK * MST];       // 104000 B
    __shared__ alignas(16) int s_k[GPIX];    //  16384 B

    const int t  = threadIdx.x;
    const int b  = blockIdx.x >> 6;
    const int p0 = (blockIdx.x & 63) * GPIX;

    // stage means (divide fused)
    const float4* ms = (const float4*)(g_sums + (size_t)b * KK * CC);
    const float*  cb = g_cnt + b * KK;
    for (int e = t; e < KK * (CC / 4); e += GTH) {
        int k = e >> 4;
        float4 v = ms[e];
        float inv = 1.0f / fmaxf(cb[k], 1.0f);
        float* dst = &s_mean[k * MST + (e & 15) * 4];
        dst[0] = v.x * inv; dst[1] = v.y * inv;
        dst[2] = v.z * inv; dst[3] = v.w * inv;
    }
    // stage idx (exactly one int4 per thread)
    {
        const int4* i4 = (const int4*)(idx + b * NPIX + p0);
        *(int4*)&s_k[t * 4] = i4[t];
    }
    __syncthreads();

    const int lane = t & 63;
    const int w    = t >> 6;
    const int isk  = (blockIdx.x + w * 5) & 15;   // start-phase rotation
    float* ob = out + (size_t)b * CC * NPIX + p0;

    for (int cc = 0; cc < 4; ++cc) {
        const int c = w * 4 + cc;
        float* oc = ob + (size_t)c * NPIX;
        for (int i = 0; i < 16; ++i) {
            const int ii = (i + isk) & 15;
            const int pb = ii * 256 + lane * 4;
            int4 kk = *(const int4*)&s_k[pb];
            float4 v;
            v.x = s_mean[kk.x * MST + c];
            v.y = s_mean[kk.y * MST + c];
            v.z = s_mean[kk.z * MST + c];
            v.w = s_mean[kk.w * MST + c];
            *(float4*)(oc + pb) = v;       // 1 KB contiguous per instr
        }
    }
}

extern "C" void kernel_launch(void* const* d_in, const int* in_sizes, int n_in,
                              void* d_out, int out_size, void* d_ws, size_t ws_size,
                              hipStream_t stream) {
    const float* feat = (const float*)d_in[0];   // [B, C, N] fp32
    const int*   idx  = (const int*)d_in[1];     // [B, N] int32
    float* out    = (float*)d_out;               // [B, C, N] fp32
    float* g_sums = (float*)d_ws;                // B*K*C floats = 409600 B
    float* g_cnt  = g_sums + BB * KK * CC;       // B*K floats   =   6400 B

    hipMemsetAsync(d_ws, 0, (size_t)(BB * KK * CC + BB * KK) * sizeof(float), stream);

    accum_kernel<<<BB * 64, ATH, 0, stream>>>(feat, idx, g_sums, g_cnt);
    gather_kernel<<<BB * 64, GTH, 0, stream>>>(g_sums, g_cnt, idx, out);
}

// Round 4
// 502.778 us; speedup vs baseline: 1.0298x; 1.0298x over previous
//
#include <hip/hip_runtime.h>

// Problem constants: B=4, C=64, N=512*512, K=400
constexpr int BB   = 4;
constexpr int CC   = 64;
constexpr int NPIX = 512 * 512;      // 262144
constexpr int KK   = 400;

// ---------------- accum config ----------------
constexpr int PPB  = 4096;           // pixels per block
constexpr int TPX  = 128;            // pixels per LDS feature tile
constexpr int NTL  = PPB / TPX;      // 32 tiles
constexpr int TSTR = TPX + 1;        // 129: read banks (c+p)%32, 2 lanes/bank = free
constexpr int ATH  = 1024;           // 16 waves
constexpr int NW   = 16;             // owner classes (k & 15), one per wave
constexpr int ADUMROW = KK * CC;     // dummy sums row for deduped duplicates

// ---------------------------------------------------------------------------
// Stage 1 (exact R2 structure — the 500 µs config; R3's memory-side tweaks
// reverted after they showed no gain):
//   - wave w owns cells with (k & 15) == w  -> plain LDS RMW race-free
//   - compaction prefix saved per pass-iteration -> counted inner loop
//   - batches of 4 pixels, reads batched ahead of writes, dedup in VALU
// grid = B * 64 chunks = 256 blocks (1 per CU), 1024 threads
// ---------------------------------------------------------------------------
__global__ __launch_bounds__(ATH) void accum_kernel(
    const float* __restrict__ feat,   // [B, C, N]
    const int*   __restrict__ idx,    // [B, N]
    float* __restrict__ g_sums,       // [B, K, C]
    float* __restrict__ g_cnt)        // [B, K]
{
    __shared__ float    s_sums[(KK + 1) * CC]; // 102656 B; row KK = dummy
    __shared__ float    s_cnt[KK];             //   1600 B
    __shared__ unsigned s_list[PPB];           //  16384 B: (pix<<16) | (k<<6)
    __shared__ float    s_tile[CC * TSTR];     //  33024 B
    __shared__ int      s_wcnt[NW];

    const int t     = threadIdx.x;
    const int lane  = t & 63;
    const int w     = t >> 6;                  // wave id 0..15 == owner class
    const int b     = blockIdx.x >> 6;
    const int chunk = blockIdx.x & 63;
    const int p0    = chunk * PPB;

    // zero LDS
    for (int e = t; e < (KK + 1) * CC; e += ATH) s_sums[e] = 0.0f;
    for (int e = t; e < KK; e += ATH) s_cnt[e] = 0.0f;
    __syncthreads();

    const int* idx_b = idx + b * NPIX + p0;
    const unsigned long long lmask = (1ull << lane) - 1ull;

    // ---- pass 1: per-wave ownership count; cell counts spread across waves ----
    int myCnt = 0;
    for (int j = 0; j < 64; ++j) {
        int k = idx_b[j * 64 + lane];
        if ((j >> 2) == w) atomicAdd(&s_cnt[k], 1.0f);
        myCnt += __popcll(__ballot((k & 15) == w));
    }
    if (lane == 0) s_wcnt[w] = myCnt;
    __syncthreads();

    int base = 0;
#pragma unroll
    for (int j = 0; j < NW; ++j) { int cj = s_wcnt[j]; base += (j < w) ? cj : 0; }

    // ---- pass 2: compact owned pixels (sorted by pixel), save prefix/lane ----
    int pos = base;
    int sp = 0, se = 0;   // lane j holds pos before/after pass-iteration j
    for (int j = 0; j < 64; ++j) {
        int i = j * 64 + lane;
        int k = idx_b[i];
        bool own = ((k & 15) == w);
        unsigned long long m = __ballot(own);
        if (lane == j) sp = pos;
        if (own) s_list[pos + __popcll(m & lmask)] =
                     ((unsigned)i << 16) | ((unsigned)k << 6);
        pos += __popcll(m);
        if (lane == j) se = pos;
    }

    // ---- tile loop ----
    const float* fb   = feat + (size_t)b * CC * NPIX + p0;
    const int    cr   = t >> 4;      // staging: channel row 0..63
    const int    gq   = t & 15;      // staging: 8-float column group
    const float* fsrc = fb + (size_t)cr * NPIX + gq * 8;
    float*       tdst = &s_tile[cr * TSTR + gq * 8];

    float4 va = *(const float4*)(fsrc);
    float4 vb = *(const float4*)(fsrc + 4);

    for (int tl = 0; tl < NTL; ++tl) {
        __syncthreads();                       // prev tile fully consumed
        tdst[0] = va.x; tdst[1] = va.y; tdst[2] = va.z; tdst[3] = va.w;
        tdst[4] = vb.x; tdst[5] = vb.y; tdst[6] = vb.z; tdst[7] = vb.w;
        __syncthreads();                       // tile staged
        if (tl + 1 < NTL) {                    // issue next load under processing
            va = *(const float4*)(fsrc + (tl + 1) * TPX);
            vb = *(const float4*)(fsrc + (tl + 1) * TPX + 4);
        }

        int cur = __builtin_amdgcn_readlane(sp, 2 * tl);
        int end = __builtin_amdgcn_readlane(se, 2 * tl + 1);

        // batches of 4 pixels: reads batched ahead of writes, dedup in VALU
        for (; cur + 4 <= end; cur += 4) {
            unsigned e0 = s_list[cur + 0];
            unsigned e1 = s_list[cur + 1];
            unsigned e2 = s_list[cur + 2];
            unsigned e3 = s_list[cur + 3];

            int m0 = (int)(e0 & 0xFFFFu), m1 = (int)(e1 & 0xFFFFu);
            int m2 = (int)(e2 & 0xFFFFu), m3 = (int)(e3 & 0xFFFFu);

            float v0 = s_tile[lane * TSTR + ((e0 >> 16) & (TPX - 1))];
            float v1 = s_tile[lane * TSTR + ((e1 >> 16) & (TPX - 1))];
            float v2 = s_tile[lane * TSTR + ((e2 >> 16) & (TPX - 1))];
            float v3 = s_tile[lane * TSTR + ((e3 >> 16) & (TPX - 1))];

            bool d10 = (m1 == m0);
            bool d20 = (m2 == m0), d21 = (m2 == m1);
            bool d30 = (m3 == m0), d31 = (m3 == m1), d32 = (m3 == m2);

            v0 += d10 ? v1 : 0.0f;
            v0 += d20 ? v2 : 0.0f;
            v1 += (!d20 && d21) ? v2 : 0.0f;
            v0 += d30 ? v3 : 0.0f;
            v1 += (!d30 && d31) ? v3 : 0.0f;
            v2 += (!d30 && !d31 && d32) ? v3 : 0.0f;

            int a0 = m0 + lane;
            int a1 = d10 ? (ADUMROW + lane) : (m1 + lane);
            int a2 = (d20 || d21) ? (ADUMROW + lane) : (m2 + lane);
            int a3 = (d30 || d31 || d32) ? (ADUMROW + lane) : (m3 + lane);

            float s0 = s_sums[a0];
            float s1 = s_sums[a1];
            float s2 = s_sums[a2];
            float s3 = s_sums[a3];
            s_sums[a0] = s0 + v0;
            s_sums[a1] = s1 + v1;
            s_sums[a2] = s2 + v2;
            s_sums[a3] = s3 + v3;
        }
        // tail (<4): serial RMW (source order keeps may-alias correctness)
        for (; cur < end; ++cur) {
            unsigned e = s_list[cur];
            int a = (int)(e & 0xFFFFu) + lane;
            s_sums[a] += s_tile[lane * TSTR + ((e >> 16) & (TPX - 1))];
        }
    }
    __syncthreads();

    // ---- merge to global ----
    float* gs = g_sums + (size_t)b * KK * CC;
    for (int e = t; e < KK * CC; e += ATH) {
        float v = s_sums[e];
        if (v != 0.0f) atomicAdd(&gs[e], v);
    }
    float* gc = g_cnt + b * KK;
    for (int e = t; e < KK; e += ATH) {
        float v = s_cnt[e];
        if (v != 0.0f) atomicAdd(&gc[e], v);
    }
}

// ---------------- gather config ----------------
constexpr int GTH  = 1024;               // 16 waves
constexpr int GPIX = 4096;               // pixels per block
constexpr int MST  = 65;                 // float stride: read bank = (k+c)%32, uniform-random

// ---------------------------------------------------------------------------
// Stage 2 (fused means + gather), BLOCK-COOPERATIVE channel sweep:
//   Per channel step, ALL 16 waves write consecutive 1 KB pieces of the SAME
//   16 KB channel-row segment -> exactly ONE active store stream per block
//   (256 streams device-wide, fill-like) instead of 16 per block (4096
//   device-wide). Each lane's 4 pixel cell-ids are hoisted to registers once
//   (coalesced int4), so the per-step work is just 4 LDS table reads + one
//   coalesced 1 KB store. No barriers in the sweep loop.
// grid = B * 64 = 256 blocks, 1024 threads
// ---------------------------------------------------------------------------
__global__ __launch_bounds__(GTH) void gather_kernel(
    const float* __restrict__ g_sums, // [B, K, C]
    const float* __restrict__ g_cnt,  // [B, K]
    const int*   __restrict__ idx,    // [B, N]
    float* __restrict__ out)          // [B, C, N]
{
    __shared__ float s_mean[KK * MST];       // 104000 B -> 1 block/CU

    const int t    = threadIdx.x;
    const int lane = t & 63;
    const int w    = t >> 6;
    const int b    = blockIdx.x >> 6;
    const int p0   = (blockIdx.x & 63) * GPIX;

    // hoist this lane's 4 pixel indices to registers (coalesced int4, once)
    int4 kk = ((const int4*)(idx + b * NPIX + p0 + w * 256))[lane];
    const int ax = kk.x * MST, ay = kk.y * MST, az = kk.z * MST, aw2 = kk.w * MST;

    // stage means (divide fused)
    const float4* ms = (const float4*)(g_sums + (size_t)b * KK * CC);
    const float*  cb = g_cnt + b * KK;
    for (int e = t; e < KK * (CC / 4); e += GTH) {
        int k = e >> 4;
        float4 v = ms[e];
        float inv = 1.0f / fmaxf(cb[k], 1.0f);
        float* dst = &s_mean[k * MST + (e & 15) * 4];
        dst[0] = v.x * inv; dst[1] = v.y * inv;
        dst[2] = v.z * inv; dst[3] = v.w * inv;
    }
    __syncthreads();

    // channel sweep: block writes one contiguous 16 KB segment per step
    float* ob = out + (size_t)b * CC * NPIX + p0 + w * 256 + lane * 4;
    const int csk = (blockIdx.x * 7) & 63;   // decorrelate rows across blocks

    for (int s = 0; s < CC; ++s) {
        const int c = (s + csk) & 63;
        float4 v;
        v.x = s_mean[ax + c];
        v.y = s_mean[ay + c];
        v.z = s_mean[az + c];
        v.w = s_mean[aw2 + c];
        *(float4*)(ob + (size_t)c * NPIX) = v;
    }
}

extern "C" void kernel_launch(void* const* d_in, const int* in_sizes, int n_in,
                              void* d_out, int out_size, void* d_ws, size_t ws_size,
                              hipStream_t stream) {
    const float* feat = (const float*)d_in[0];   // [B, C, N] fp32
    const int*   idx  = (const int*)d_in[1];     // [B, N] int32
    float* out    = (float*)d_out;               // [B, C, N] fp32
    float* g_sums = (float*)d_ws;                // B*K*C floats = 409600 B
    float* g_cnt  = g_sums + BB * KK * CC;       // B*K floats   =   6400 B

    hipMemsetAsync(d_ws, 0, (size_t)(BB * KK * CC + BB * KK) * sizeof(float), stream);

    accum_kernel<<<BB * 64, ATH, 0, stream>>>(feat, idx, g_sums, g_cnt);
    gather_kernel<<<BB * 64, GTH, 0, stream>>>(g_sums, g_cnt, idx, out);
}